// Round 1
// baseline (297.493 us; speedup 1.0000x reference)
//
#include <hip/hip_runtime.h>
#include <cstddef>
#include <cstdint>

#define LRELU(v) ((v) > 0.f ? (v) : 0.2f * (v))
#define NEG_INF -3.4e38f

// ---------------- CSR build ----------------

__global__ void k_deg_init(int* deg, int N) {
    int i = blockIdx.x * blockDim.x + threadIdx.x;
    if (i < N) deg[i] = 1;  // self-loop
}

__global__ void k_hist(const int* src, const int* dst, int* deg, int E) {
    int e = blockIdx.x * blockDim.x + threadIdx.x;
    if (e < E) {
        int s = src[e], d = dst[e];
        if (s != d) atomicAdd(&deg[d], 1);  // masked self-edges dropped
    }
}

__global__ __launch_bounds__(1024) void k_scan(const int* deg, int* offs, int* cursor, int N) {
    __shared__ int part[1024];
    int t = threadIdx.x;
    int chunk = (N + 1023) >> 10;
    int start = t * chunk;
    int s = 0;
    for (int i = 0; i < chunk; i++) {
        int idx = start + i;
        if (idx < N) s += deg[idx];
    }
    part[t] = s;
    __syncthreads();
    for (int off = 1; off < 1024; off <<= 1) {
        int v = (t >= off) ? part[t - off] : 0;
        __syncthreads();
        part[t] += v;
        __syncthreads();
    }
    int run = part[t] - s;  // exclusive prefix of this thread's chunk
    for (int i = 0; i < chunk; i++) {
        int idx = start + i;
        if (idx < N) {
            offs[idx] = run;
            cursor[idx] = run;
            run += deg[idx];
        }
    }
    if (t == 1023) offs[N] = part[1023];
}

__global__ void k_fill(const int* src, const int* dst, int* cursor, int* csr, int E, int N) {
    int e = blockIdx.x * blockDim.x + threadIdx.x;
    if (e < E) {
        int s = src[e], d = dst[e];
        if (s != d) {
            int pos = atomicAdd(&cursor[d], 1);
            csr[pos] = s;
        }
    } else if (e < E + N) {
        int i = e - E;
        int pos = atomicAdd(&cursor[i], 1);
        csr[pos] = i;
    }
}

// ---------------- fold W2 with a_src2/a_dst2 -> [64,8] each ----------------

__global__ __launch_bounds__(512) void k_fold(const float* W2, const float* a_src2,
                                              const float* a_dst2, float* wfold) {
    int u = threadIdx.x;  // 512 = 64 k * 8 h
    int k = u >> 3, h = u & 7;
    float ss = 0.f, sd = 0.f;
    for (int c = 0; c < 128; c++) {
        float w = W2[k * 1024 + h * 128 + c];
        ss += w * a_src2[h * 128 + c];
        sd += w * a_dst2[h * 128 + c];
    }
    wfold[u] = ss;        // w_s2[k*8+h]
    wfold[512 + u] = sd;  // w_d2[k*8+h]
}

// ---------------- layer 1 GEMM: h1 = x @ W1, plus alpha_s1/alpha_d1 ----------------

__global__ __launch_bounds__(64) void k_gemm1(const float* x, const float* W1,
                                              const float* a_src1, const float* a_dst1,
                                              float* h1, float* as1, float* ad1, int N) {
    __shared__ float xs[4][128];
    int t = threadIdx.x;
    int n0 = blockIdx.x * 4;
    for (int i = 0; i < 8; i++) {
        int idx = t + i * 64;
        int r = idx >> 7, c = idx & 127;
        int n = n0 + r;
        xs[r][c] = (n < N) ? x[(size_t)n * 128 + c] : 0.f;
    }
    __syncthreads();
    float acc[4] = {0.f, 0.f, 0.f, 0.f};
    for (int k = 0; k < 128; k++) {
        float w = W1[k * 64 + t];
        acc[0] += xs[0][k] * w;
        acc[1] += xs[1][k] * w;
        acc[2] += xs[2][k] * w;
        acc[3] += xs[3][k] * w;
    }
    float was = a_src1[t], wad = a_dst1[t];
    for (int m = 0; m < 4; m++) {
        int n = n0 + m;
        if (n >= N) break;
        h1[(size_t)n * 64 + t] = acc[m];
        float ps = acc[m] * was, pd = acc[m] * wad;
        ps += __shfl_xor(ps, 1); ps += __shfl_xor(ps, 2); ps += __shfl_xor(ps, 4);
        pd += __shfl_xor(pd, 1); pd += __shfl_xor(pd, 2); pd += __shfl_xor(pd, 4);
        if ((t & 7) == 0) {
            as1[n * 8 + (t >> 3)] = ps;
            ad1[n * 8 + (t >> 3)] = pd;
        }
    }
}

// ---------------- layer 1 aggregation + bias + ELU + layer-2 alpha fold ----------------

__global__ __launch_bounds__(64) void k_agg1(const int* offs, const int* csr, const float* h1,
                                             const float* as1, const float* ad1, const float* b1,
                                             const float* wfold, float* z, float* as2, float* ad2,
                                             int N) {
    int d = blockIdx.x, t = threadIdx.x, h = t >> 3;
    float adv = ad1[d * 8 + h];
    int beg = offs[d], end = offs[d + 1];
    float m = NEG_INF, l = 0.f, acc = 0.f;
    for (int j = beg; j < end; j++) {
        int s = csr[j];
        float e = as1[s * 8 + h] + adv;
        e = LRELU(e);
        float hv = h1[(size_t)s * 64 + t];
        if (e <= m) {
            float p = __expf(e - m);
            l += p;
            acc += p * hv;
        } else {
            float sc = __expf(m - e);
            l = l * sc + 1.f;
            acc = acc * sc + hv;
            m = e;
        }
    }
    float val = acc / (l + 1e-16f) + b1[t];
    float zv = val > 0.f ? val : __expf(val) - 1.f;  // ELU
    z[(size_t)d * 64 + t] = zv;
    __shared__ float zr[64];
    zr[t] = zv;
    __syncthreads();
    if (t < 16) {
        int hh = t & 7;
        const float* wf = wfold + (t < 8 ? 0 : 512);
        float s = 0.f;
        for (int k = 0; k < 64; k++) s += zr[k] * wf[k * 8 + hh];
        if (t < 8) as2[d * 8 + hh] = s;
        else       ad2[d * 8 + hh] = s;
    }
}

// ---------------- layer 2 aggregation into agg[N,8,64] (pre-GEMM features) ----------------

__global__ __launch_bounds__(64) void k_agg2(const int* offs, const int* csr, const float* z,
                                             const float* as2, const float* ad2, float* agg,
                                             int N) {
    int d = blockIdx.x, t = threadIdx.x;
    float adv[8], m[8], l[8], acc[8];
#pragma unroll
    for (int h = 0; h < 8; h++) {
        adv[h] = ad2[d * 8 + h];
        m[h] = NEG_INF;
        l[h] = 0.f;
        acc[h] = 0.f;
    }
    int beg = offs[d], end = offs[d + 1];
    for (int j = beg; j < end; j++) {
        int s = csr[j];
        float zv = z[(size_t)s * 64 + t];
#pragma unroll
        for (int h = 0; h < 8; h++) {
            float e = as2[s * 8 + h] + adv[h];
            e = LRELU(e);
            if (e <= m[h]) {  // wave-uniform branch
                float p = __expf(e - m[h]);
                l[h] += p;
                acc[h] += p * zv;
            } else {
                float sc = __expf(m[h] - e);
                l[h] = l[h] * sc + 1.f;
                acc[h] = acc[h] * sc + zv;
                m[h] = e;
            }
        }
    }
#pragma unroll
    for (int h = 0; h < 8; h++)
        agg[(size_t)d * 512 + h * 64 + t] = acc[h] / (l[h] + 1e-16f);
}

// ---------------- final block-diagonal GEMM + bias + log_softmax ----------------

__global__ __launch_bounds__(256) void k_out(const float* agg, const float* W2, const float* b2,
                                             float* out, int N) {
    __shared__ float sa[4096];  // 8 nodes x 512
    __shared__ float red[4][8];
    int t = threadIdx.x;
    int n0 = blockIdx.x * 8;
    for (int i = 0; i < 16; i++) {
        int idx = t + i * 256;
        int r = idx >> 9, c = idx & 511;
        int n = n0 + r;
        sa[idx] = (n < N) ? agg[(size_t)n * 512 + c] : 0.f;
    }
    __syncthreads();
    int ch0 = t, ch1 = t + 256, ch2 = t + 512, ch3 = t + 768;
    int hd0 = ch0 >> 7, hd1 = ch1 >> 7, hd2 = ch2 >> 7, hd3 = ch3 >> 7;
    float acc[8][4];
    float bb0 = b2[ch0], bb1 = b2[ch1], bb2 = b2[ch2], bb3 = b2[ch3];
#pragma unroll
    for (int mi = 0; mi < 8; mi++) {
        acc[mi][0] = bb0; acc[mi][1] = bb1; acc[mi][2] = bb2; acc[mi][3] = bb3;
    }
    for (int k = 0; k < 64; k++) {
        float w0 = W2[k * 1024 + ch0];
        float w1 = W2[k * 1024 + ch1];
        float w2 = W2[k * 1024 + ch2];
        float w3 = W2[k * 1024 + ch3];
#pragma unroll
        for (int mi = 0; mi < 8; mi++) {
            const float* s = &sa[mi * 512];
            acc[mi][0] += s[hd0 * 64 + k] * w0;  // LDS broadcast (uniform per wave)
            acc[mi][1] += s[hd1 * 64 + k] * w1;
            acc[mi][2] += s[hd2 * 64 + k] * w2;
            acc[mi][3] += s[hd3 * 64 + k] * w3;
        }
    }
    // log_softmax over 1024 channels per node
    int wave = t >> 6, lane = t & 63;
    float gmax[8], logZ[8];
#pragma unroll
    for (int mi = 0; mi < 8; mi++) {
        float v = fmaxf(fmaxf(acc[mi][0], acc[mi][1]), fmaxf(acc[mi][2], acc[mi][3]));
        for (int off = 32; off; off >>= 1) v = fmaxf(v, __shfl_xor(v, off));
        if (lane == 0) red[wave][mi] = v;
    }
    __syncthreads();
#pragma unroll
    for (int mi = 0; mi < 8; mi++)
        gmax[mi] = fmaxf(fmaxf(red[0][mi], red[1][mi]), fmaxf(red[2][mi], red[3][mi]));
    __syncthreads();
#pragma unroll
    for (int mi = 0; mi < 8; mi++) {
        float v = __expf(acc[mi][0] - gmax[mi]) + __expf(acc[mi][1] - gmax[mi]) +
                  __expf(acc[mi][2] - gmax[mi]) + __expf(acc[mi][3] - gmax[mi]);
        for (int off = 32; off; off >>= 1) v += __shfl_xor(v, off);
        if (lane == 0) red[wave][mi] = v;
    }
    __syncthreads();
#pragma unroll
    for (int mi = 0; mi < 8; mi++) {
        float gs = red[0][mi] + red[1][mi] + red[2][mi] + red[3][mi];
        logZ[mi] = gmax[mi] + __logf(gs);
    }
#pragma unroll
    for (int mi = 0; mi < 8; mi++) {
        int n = n0 + mi;
        if (n >= N) continue;
        size_t base = (size_t)n * 1024;
        out[base + ch0] = acc[mi][0] - logZ[mi];
        out[base + ch1] = acc[mi][1] - logZ[mi];
        out[base + ch2] = acc[mi][2] - logZ[mi];
        out[base + ch3] = acc[mi][3] - logZ[mi];
    }
}

// ---------------- launch ----------------

extern "C" void kernel_launch(void* const* d_in, const int* in_sizes, int n_in,
                              void* d_out, int out_size, void* d_ws, size_t ws_size,
                              hipStream_t stream) {
    const float* x      = (const float*)d_in[0];
    const int*   ei     = (const int*)d_in[1];
    const float* W1     = (const float*)d_in[2];
    const float* a_src1 = (const float*)d_in[3];
    const float* a_dst1 = (const float*)d_in[4];
    const float* b1     = (const float*)d_in[5];
    const float* W2     = (const float*)d_in[6];
    const float* a_src2 = (const float*)d_in[7];
    const float* a_dst2 = (const float*)d_in[8];
    const float* b2     = (const float*)d_in[9];
    float* out = (float*)d_out;

    int N = in_sizes[0] / 128;
    int E = in_sizes[1] / 2;
    const int* src = ei;
    const int* dst = ei + E;

    // workspace carve (256B-aligned regions)
    char* p = (char*)d_ws;
    auto carve = [&](size_t bytes) {
        void* r = (void*)p;
        p += (bytes + 255) & ~(size_t)255;
        return r;
    };
    int*   deg    = (int*)carve((size_t)N * 4);
    int*   offs   = (int*)carve((size_t)(N + 1) * 4);
    int*   cursor = (int*)carve((size_t)N * 4);
    int*   csr    = (int*)carve((size_t)(E + N) * 4);
    float* h1     = (float*)carve((size_t)N * 64 * 4);
    float* as1    = (float*)carve((size_t)N * 8 * 4);
    float* ad1    = (float*)carve((size_t)N * 8 * 4);
    float* z      = (float*)carve((size_t)N * 64 * 4);
    float* as2    = (float*)carve((size_t)N * 8 * 4);
    float* ad2    = (float*)carve((size_t)N * 8 * 4);
    float* wfold  = (float*)carve((size_t)1024 * 4);
    float* agg    = (float*)carve((size_t)N * 512 * 4);

    // CSR build
    k_deg_init<<<(N + 255) / 256, 256, 0, stream>>>(deg, N);
    k_hist<<<(E + 255) / 256, 256, 0, stream>>>(src, dst, deg, E);
    k_scan<<<1, 1024, 0, stream>>>(deg, offs, cursor, N);
    k_fill<<<(E + N + 255) / 256, 256, 0, stream>>>(src, dst, cursor, csr, E, N);

    // fold W2 with attention vectors
    k_fold<<<1, 512, 0, stream>>>(W2, a_src2, a_dst2, wfold);

    // layer 1
    k_gemm1<<<(N + 3) / 4, 64, 0, stream>>>(x, W1, a_src1, a_dst1, h1, as1, ad1, N);
    k_agg1<<<N, 64, 0, stream>>>(offs, csr, h1, as1, ad1, b1, wfold, z, as2, ad2, N);

    // layer 2
    k_agg2<<<N, 64, 0, stream>>>(offs, csr, z, as2, ad2, agg, N);
    k_out<<<(N + 7) / 8, 256, 0, stream>>>(agg, W2, b2, out, N);
}

// Round 2
// 280.289 us; speedup vs baseline: 1.0614x; 1.0614x over previous
//
#include <hip/hip_runtime.h>
#include <cstddef>
#include <cstdint>

#define LRELU(v) ((v) > 0.f ? (v) : 0.2f * (v))

// ---------------- CSR build ----------------

__global__ void k_deg_init(int* deg, int N) {
    int i = blockIdx.x * blockDim.x + threadIdx.x;
    if (i < N) deg[i] = 1;  // self-loop
}

__global__ void k_hist(const int* src, const int* dst, int* deg, int E) {
    int e = blockIdx.x * blockDim.x + threadIdx.x;
    if (e < E) {
        int s = src[e], d = dst[e];
        if (s != d) atomicAdd(&deg[d], 1);  // masked self-edges dropped
    }
}

__global__ __launch_bounds__(1024) void k_scan(const int* deg, int* offs, int* cursor, int N) {
    __shared__ int part[1024];
    int t = threadIdx.x;
    int chunk = (N + 1023) >> 10;
    int start = t * chunk;
    int s = 0;
    for (int i = 0; i < chunk; i++) {
        int idx = start + i;
        if (idx < N) s += deg[idx];
    }
    part[t] = s;
    __syncthreads();
    for (int off = 1; off < 1024; off <<= 1) {
        int v = (t >= off) ? part[t - off] : 0;
        __syncthreads();
        part[t] += v;
        __syncthreads();
    }
    int run = part[t] - s;  // exclusive prefix of this thread's chunk
    for (int i = 0; i < chunk; i++) {
        int idx = start + i;
        if (idx < N) {
            offs[idx] = run;
            cursor[idx] = run;
            run += deg[idx];
        }
    }
    if (t == 1023) offs[N] = part[1023];
}

__global__ void k_fill(const int* src, const int* dst, int* cursor, int* csr, int E, int N) {
    int e = blockIdx.x * blockDim.x + threadIdx.x;
    if (e < E) {
        int s = src[e], d = dst[e];
        if (s != d) {
            int pos = atomicAdd(&cursor[d], 1);
            csr[pos] = s;
        }
    } else if (e < E + N) {
        int i = e - E;
        int pos = atomicAdd(&cursor[i], 1);
        csr[pos] = i;
    }
}

// ---------------- fold W2 with a_src2/a_dst2 -> [64,8] each ----------------

__global__ __launch_bounds__(512) void k_fold(const float* W2, const float* a_src2,
                                              const float* a_dst2, float* wfold) {
    int u = threadIdx.x;  // 512 = 64 k * 8 h
    int k = u >> 3, h = u & 7;
    float ss = 0.f, sd = 0.f;
    for (int c = 0; c < 128; c++) {
        float w = W2[k * 1024 + h * 128 + c];
        ss += w * a_src2[h * 128 + c];
        sd += w * a_dst2[h * 128 + c];
    }
    wfold[u] = ss;        // w_s2[k*8+h]
    wfold[512 + u] = sd;  // w_d2[k*8+h]
}

// ---------------- layer 1 GEMM: h1 = x @ W1, plus alpha_s1/alpha_d1 ----------------

__global__ __launch_bounds__(64) void k_gemm1(const float* x, const float* W1,
                                              const float* a_src1, const float* a_dst1,
                                              float* h1, float* as1, float* ad1, int N) {
    __shared__ float xs[4][128];
    int t = threadIdx.x;
    int n0 = blockIdx.x * 4;
    for (int i = 0; i < 8; i++) {
        int idx = t + i * 64;
        int r = idx >> 7, c = idx & 127;
        int n = n0 + r;
        xs[r][c] = (n < N) ? x[(size_t)n * 128 + c] : 0.f;
    }
    __syncthreads();
    float acc[4] = {0.f, 0.f, 0.f, 0.f};
    for (int k = 0; k < 128; k++) {
        float w = W1[k * 64 + t];
        acc[0] += xs[0][k] * w;
        acc[1] += xs[1][k] * w;
        acc[2] += xs[2][k] * w;
        acc[3] += xs[3][k] * w;
    }
    float was = a_src1[t], wad = a_dst1[t];
    for (int m = 0; m < 4; m++) {
        int n = n0 + m;
        if (n >= N) break;
        h1[(size_t)n * 64 + t] = acc[m];
        float ps = acc[m] * was, pd = acc[m] * wad;
        ps += __shfl_xor(ps, 1); ps += __shfl_xor(ps, 2); ps += __shfl_xor(ps, 4);
        pd += __shfl_xor(pd, 1); pd += __shfl_xor(pd, 2); pd += __shfl_xor(pd, 4);
        if ((t & 7) == 0) {
            as1[n * 8 + (t >> 3)] = ps;
            ad1[n * 8 + (t >> 3)] = pd;
        }
    }
}

// ---------------- normalized attention weights (shared by both layers) ----------------
// One wave per dst node; lane = el*8 + h covers 8 edges x 8 heads per iter.
// Writes alpha[j*8+h] in CSR order (fully coalesced).

__global__ __launch_bounds__(256) void k_alpha(const int* offs, const int* csr,
                                               const float* as, const float* ad,
                                               float* alpha, int N) {
    int node = blockIdx.x * 4 + (threadIdx.x >> 6);
    if (node >= N) return;
    int lane = threadIdx.x & 63;
    int el = lane >> 3, h = lane & 7;
    float adv = ad[node * 8 + h];
    int beg = offs[node], end = offs[node + 1];
    float m = -1e30f, l = 0.f;
    for (int j0 = beg; j0 < end; j0 += 8) {
        int j = j0 + el;
        float e = -1e30f;
        if (j < end) {
            int s = csr[j];
            float v = as[s * 8 + h] + adv;
            e = LRELU(v);
        }
        float nm = fmaxf(m, e);
        float t1 = l * __expf(m - nm);               // l==0 kills the exp(0) NaN-guard case
        float t2 = (j < end) ? __expf(e - nm) : 0.f;
        l = t1 + t2;
        m = nm;
    }
    // reduce (m,l) across the 8 edge-groups (stride-8 lanes)
    for (int off = 8; off < 64; off <<= 1) {
        float m2 = __shfl_xor(m, off);
        float l2 = __shfl_xor(l, off);
        float nm = fmaxf(m, m2);
        l = l * __expf(m - nm) + l2 * __expf(m2 - nm);
        m = nm;
    }
    float inv = 1.f / (l + 1e-16f);
    for (int j0 = beg; j0 < end; j0 += 8) {
        int j = j0 + el;
        if (j < end) {
            int s = csr[j];
            float v = as[s * 8 + h] + adv;
            float e = LRELU(v);
            alpha[(size_t)j * 8 + h] = __expf(e - m) * inv;
        }
    }
}

// ---------------- layer 1 aggregation + bias + ELU + layer-2 alpha fold ----------------

__global__ __launch_bounds__(256) void k_agg1(const int* offs, const int* csr, const float* h1,
                                              const float* alpha, const float* b1,
                                              const float* wfold, float* z, float* as2,
                                              float* ad2, int N) {
    __shared__ float zr[4][64];
    int warp = threadIdx.x >> 6;
    int node = blockIdx.x * 4 + warp;
    int t = threadIdx.x & 63;
    bool valid = node < N;
    float zv = 0.f;
    if (valid) {
        int beg = offs[node], end = offs[node + 1];
        int h = t >> 3;
        float acc = 0.f;
        for (int j = beg; j < end; j++) {
            int s = csr[j];
            float a = alpha[(size_t)j * 8 + h];
            acc += a * h1[(size_t)s * 64 + t];
        }
        float val = acc + b1[t];
        zv = val > 0.f ? val : __expf(val) - 1.f;  // ELU
        z[(size_t)node * 64 + t] = zv;
    }
    zr[warp][t] = zv;
    __syncthreads();
    if (valid && t < 16) {
        int hh = t & 7;
        const float* wf = wfold + (t < 8 ? 0 : 512);
        float s = 0.f;
        for (int k = 0; k < 64; k++) s += zr[warp][k] * wf[k * 8 + hh];
        if (t < 8) as2[node * 8 + hh] = s;
        else       ad2[node * 8 + hh] = s;
    }
}

// ---------------- layer 2 aggregation into agg[N,8,64] (pre-GEMM features) ----------------

__global__ __launch_bounds__(256) void k_agg2(const int* offs, const int* csr, const float* z,
                                              const float* alpha, float* agg, int N) {
    int node = blockIdx.x * 4 + (threadIdx.x >> 6);
    if (node >= N) return;
    int t = threadIdx.x & 63;
    int beg = offs[node], end = offs[node + 1];
    float acc[8] = {0.f, 0.f, 0.f, 0.f, 0.f, 0.f, 0.f, 0.f};
    for (int j = beg; j < end; j++) {
        int s = csr[j];
        float zvv = z[(size_t)s * 64 + t];
        const float4* ap = (const float4*)(alpha + (size_t)j * 8);
        float4 a0 = ap[0], a1 = ap[1];
        acc[0] += a0.x * zvv; acc[1] += a0.y * zvv;
        acc[2] += a0.z * zvv; acc[3] += a0.w * zvv;
        acc[4] += a1.x * zvv; acc[5] += a1.y * zvv;
        acc[6] += a1.z * zvv; acc[7] += a1.w * zvv;
    }
#pragma unroll
    for (int h = 0; h < 8; h++)
        agg[(size_t)node * 512 + h * 64 + t] = acc[h];
}

// ---------------- final per-head GEMM + bias + log_softmax ----------------

__global__ __launch_bounds__(256) void k_out(const float* agg, const float* W2, const float* b2,
                                             float* out, int N) {
    __shared__ float sa[4096];  // 8 nodes x 512
    __shared__ float red[4][8];
    int t = threadIdx.x;
    int n0 = blockIdx.x * 8;
    for (int i = 0; i < 16; i++) {
        int idx = t + i * 256;
        int r = idx >> 9, c = idx & 511;
        int n = n0 + r;
        sa[idx] = (n < N) ? agg[(size_t)n * 512 + c] : 0.f;
    }
    __syncthreads();
    int ch0 = t, ch1 = t + 256, ch2 = t + 512, ch3 = t + 768;
    int hd0 = ch0 >> 7, hd1 = ch1 >> 7, hd2 = ch2 >> 7, hd3 = ch3 >> 7;
    float acc[8][4];
    float bb0 = b2[ch0], bb1 = b2[ch1], bb2 = b2[ch2], bb3 = b2[ch3];
#pragma unroll
    for (int mi = 0; mi < 8; mi++) {
        acc[mi][0] = bb0; acc[mi][1] = bb1; acc[mi][2] = bb2; acc[mi][3] = bb3;
    }
    for (int k = 0; k < 64; k++) {
        float w0 = W2[k * 1024 + ch0];
        float w1 = W2[k * 1024 + ch1];
        float w2 = W2[k * 1024 + ch2];
        float w3 = W2[k * 1024 + ch3];
#pragma unroll
        for (int mi = 0; mi < 8; mi++) {
            const float* s = &sa[mi * 512];
            acc[mi][0] += s[hd0 * 64 + k] * w0;  // LDS broadcast (uniform per wave)
            acc[mi][1] += s[hd1 * 64 + k] * w1;
            acc[mi][2] += s[hd2 * 64 + k] * w2;
            acc[mi][3] += s[hd3 * 64 + k] * w3;
        }
    }
    // log_softmax over 1024 channels per node
    int wave = t >> 6, lane = t & 63;
    float gmax[8], logZ[8];
#pragma unroll
    for (int mi = 0; mi < 8; mi++) {
        float v = fmaxf(fmaxf(acc[mi][0], acc[mi][1]), fmaxf(acc[mi][2], acc[mi][3]));
        for (int off = 32; off; off >>= 1) v = fmaxf(v, __shfl_xor(v, off));
        if (lane == 0) red[wave][mi] = v;
    }
    __syncthreads();
#pragma unroll
    for (int mi = 0; mi < 8; mi++)
        gmax[mi] = fmaxf(fmaxf(red[0][mi], red[1][mi]), fmaxf(red[2][mi], red[3][mi]));
    __syncthreads();
#pragma unroll
    for (int mi = 0; mi < 8; mi++) {
        float v = __expf(acc[mi][0] - gmax[mi]) + __expf(acc[mi][1] - gmax[mi]) +
                  __expf(acc[mi][2] - gmax[mi]) + __expf(acc[mi][3] - gmax[mi]);
        for (int off = 32; off; off >>= 1) v += __shfl_xor(v, off);
        if (lane == 0) red[wave][mi] = v;
    }
    __syncthreads();
#pragma unroll
    for (int mi = 0; mi < 8; mi++) {
        float gs = red[0][mi] + red[1][mi] + red[2][mi] + red[3][mi];
        logZ[mi] = gmax[mi] + __logf(gs);
    }
#pragma unroll
    for (int mi = 0; mi < 8; mi++) {
        int n = n0 + mi;
        if (n >= N) continue;
        size_t base = (size_t)n * 1024;
        out[base + ch0] = acc[mi][0] - logZ[mi];
        out[base + ch1] = acc[mi][1] - logZ[mi];
        out[base + ch2] = acc[mi][2] - logZ[mi];
        out[base + ch3] = acc[mi][3] - logZ[mi];
    }
}

// ---------------- launch ----------------

extern "C" void kernel_launch(void* const* d_in, const int* in_sizes, int n_in,
                              void* d_out, int out_size, void* d_ws, size_t ws_size,
                              hipStream_t stream) {
    const float* x      = (const float*)d_in[0];
    const int*   ei     = (const int*)d_in[1];
    const float* W1     = (const float*)d_in[2];
    const float* a_src1 = (const float*)d_in[3];
    const float* a_dst1 = (const float*)d_in[4];
    const float* b1     = (const float*)d_in[5];
    const float* W2     = (const float*)d_in[6];
    const float* a_src2 = (const float*)d_in[7];
    const float* a_dst2 = (const float*)d_in[8];
    const float* b2     = (const float*)d_in[9];
    float* out = (float*)d_out;

    int N = in_sizes[0] / 128;
    int E = in_sizes[1] / 2;
    const int* src = ei;
    const int* dst = ei + E;

    // workspace carve (256B-aligned regions)
    char* p = (char*)d_ws;
    auto carve = [&](size_t bytes) {
        void* r = (void*)p;
        p += (bytes + 255) & ~(size_t)255;
        return r;
    };
    int*   deg    = (int*)carve((size_t)N * 4);
    int*   offs   = (int*)carve((size_t)(N + 1) * 4);
    int*   cursor = (int*)carve((size_t)N * 4);
    int*   csr    = (int*)carve((size_t)(E + N) * 4);
    float* h1     = (float*)carve((size_t)N * 64 * 4);
    float* as1    = (float*)carve((size_t)N * 8 * 4);
    float* ad1    = (float*)carve((size_t)N * 8 * 4);
    float* z      = (float*)carve((size_t)N * 64 * 4);
    float* as2    = (float*)carve((size_t)N * 8 * 4);
    float* ad2    = (float*)carve((size_t)N * 8 * 4);
    float* wfold  = (float*)carve((size_t)1024 * 4);
    float* alpha  = (float*)carve((size_t)(E + N) * 8 * 4);  // reused by both layers
    float* agg    = (float*)carve((size_t)N * 512 * 4);

    int nb4 = (N + 3) / 4;

    // CSR build
    k_deg_init<<<(N + 255) / 256, 256, 0, stream>>>(deg, N);
    k_hist<<<(E + 255) / 256, 256, 0, stream>>>(src, dst, deg, E);
    k_scan<<<1, 1024, 0, stream>>>(deg, offs, cursor, N);
    k_fill<<<(E + N + 255) / 256, 256, 0, stream>>>(src, dst, cursor, csr, E, N);

    // fold W2 with attention vectors
    k_fold<<<1, 512, 0, stream>>>(W2, a_src2, a_dst2, wfold);

    // layer 1
    k_gemm1<<<(N + 3) / 4, 64, 0, stream>>>(x, W1, a_src1, a_dst1, h1, as1, ad1, N);
    k_alpha<<<nb4, 256, 0, stream>>>(offs, csr, as1, ad1, alpha, N);
    k_agg1<<<nb4, 256, 0, stream>>>(offs, csr, h1, alpha, b1, wfold, z, as2, ad2, N);

    // layer 2
    k_alpha<<<nb4, 256, 0, stream>>>(offs, csr, as2, ad2, alpha, N);
    k_agg2<<<nb4, 256, 0, stream>>>(offs, csr, z, alpha, agg, N);
    k_out<<<(N + 7) / 8, 256, 0, stream>>>(agg, W2, b2, out, N);
}